// Round 1
// baseline (1624.455 us; speedup 1.0000x reference)
//
#include <hip/hip_runtime.h>

#define FEAT 128

// ---- degree = 1 (self-loop) + count of dst occurrences ----
__global__ void k_deg_init(float* __restrict__ deg, int N) {
    int i = blockIdx.x * blockDim.x + threadIdx.x;
    if (i < N) deg[i] = 1.0f;
}

__global__ void k_deg_count(const int* __restrict__ dst, float* __restrict__ deg, int E) {
    int i = blockIdx.x * blockDim.x + threadIdx.x;
    if (i < E) atomicAdd(&deg[dst[i]], 1.0f);
}

__global__ void k_rsqrt(float* __restrict__ deg, int N) {
    int i = blockIdx.x * blockDim.x + threadIdx.x;
    if (i < N) deg[i] = rsqrtf(deg[i]);  // deg >= 1 always (self-loop)
}

// ---- out[n] = dinv[n]^2 * x[n]  (self-loop term; also fully initializes d_out) ----
__global__ void k_selfloop(const float* __restrict__ x, const float* __restrict__ dinv,
                           float* __restrict__ out, int N) {
    int t = blockIdx.x * blockDim.x + threadIdx.x;
    int n = t >> 5;       // 32 threads (float4 each) per node row of 128 floats
    int c = t & 31;
    if (n >= N) return;
    float s = dinv[n];
    s *= s;
    float4 v = ((const float4*)(x + (size_t)n * FEAT))[c];
    v.x *= s; v.y *= s; v.z *= s; v.w *= s;
    ((float4*)(out + (size_t)n * FEAT))[c] = v;
}

// ---- one wave per edge: out[dst] += dinv[src]*dinv[dst] * x[src] ----
__global__ void k_scatter(const int* __restrict__ src, const int* __restrict__ dst,
                          const float* __restrict__ dinv, const float* __restrict__ x,
                          float* __restrict__ out, int E) {
    long long gid = (long long)blockIdx.x * blockDim.x + threadIdx.x;
    long long e = gid >> 6;
    int lane = threadIdx.x & 63;
    if (e >= E) return;
    int s = src[e], d = dst[e];
    float nrm = dinv[s] * dinv[d];
    const float* xs = x + (size_t)s * FEAT;
    float* od = out + (size_t)d * FEAT;
    atomicAdd(&od[lane],      nrm * xs[lane]);
    atomicAdd(&od[lane + 64], nrm * xs[lane + 64]);
}

// ---- in-place GEMM: out[n] = y[n] @ W + b  (y == out rows; barrier splits read/write) ----
__global__ __launch_bounds__(256) void k_gemm_inplace(float* __restrict__ out,
                                                      const float* __restrict__ W,
                                                      const float* __restrict__ b, int N) {
    __shared__ float Wl[FEAT * FEAT];  // 64 KB
    int tid = threadIdx.x;
    for (int i = tid; i < FEAT * FEAT / 4; i += 256)
        ((float4*)Wl)[i] = ((const float4*)W)[i];
    __syncthreads();

    int j = tid & 127;          // output column
    int half = tid >> 7;        // 0: rows 0..7, 1: rows 8..15 of this block
    int row0 = blockIdx.x * 16 + half * 8;
    // row0 is wave-uniform (wave = 64 lanes, halves are wave-aligned) -> force SGPR
    row0 = __builtin_amdgcn_readfirstlane(row0);

    float bj = b[j];
    float acc[8];
#pragma unroll
    for (int r = 0; r < 8; ++r) acc[r] = bj;

    const float* Y = out + (size_t)row0 * FEAT;
    bool full = (row0 + 8 <= N);
    if (full) {
#pragma unroll 4
        for (int f = 0; f < FEAT; ++f) {
            float w = Wl[f * FEAT + j];
#pragma unroll
            for (int r = 0; r < 8; ++r) acc[r] += w * Y[(size_t)r * FEAT + f];
        }
    } else {
        for (int f = 0; f < FEAT; ++f) {
            float w = Wl[f * FEAT + j];
            for (int r = 0; r < 8; ++r)
                if (row0 + r < N) acc[r] += w * Y[(size_t)r * FEAT + f];
        }
    }
    __syncthreads();  // all reads of this block's rows done before any write
    if (full) {
#pragma unroll
        for (int r = 0; r < 8; ++r) out[(size_t)(row0 + r) * FEAT + j] = acc[r];
    } else {
        for (int r = 0; r < 8; ++r)
            if (row0 + r < N) out[(size_t)(row0 + r) * FEAT + j] = acc[r];
    }
}

extern "C" void kernel_launch(void* const* d_in, const int* in_sizes, int n_in,
                              void* d_out, int out_size, void* d_ws, size_t ws_size,
                              hipStream_t stream) {
    const float* x = (const float*)d_in[0];
    const int*   ei = (const int*)d_in[1];   // int32 (JAX x64 disabled)
    const float* W = (const float*)d_in[2];
    const float* b = (const float*)d_in[3];
    float* out = (float*)d_out;

    int N = in_sizes[0] / FEAT;
    int E = in_sizes[1] / 2;
    const int* src = ei;
    const int* dst = ei + E;

    float* deg = (float*)d_ws;  // N floats; becomes dinv in place

    const int bs = 256;
    k_deg_init<<<(N + bs - 1) / bs, bs, 0, stream>>>(deg, N);
    k_deg_count<<<(E + bs - 1) / bs, bs, 0, stream>>>(dst, deg, E);
    k_rsqrt<<<(N + bs - 1) / bs, bs, 0, stream>>>(deg, N);

    long long t_sl = (long long)N * 32;
    k_selfloop<<<(int)((t_sl + bs - 1) / bs), bs, 0, stream>>>(x, deg, out, N);

    long long t_sc = (long long)E * 64;
    k_scatter<<<(int)((t_sc + bs - 1) / bs), bs, 0, stream>>>(src, dst, deg, x, out, E);

    k_gemm_inplace<<<(N + 15) / 16, 256, 0, stream>>>(out, W, b, N);
}

// Round 2
// 804.562 us; speedup vs baseline: 2.0191x; 2.0191x over previous
//
#include <hip/hip_runtime.h>

#define FEAT 128

// ======================= common small kernels =======================

__global__ void k_zero_i32(int* __restrict__ p, int n) {
    int i = blockIdx.x * blockDim.x + threadIdx.x;
    if (i < n) p[i] = 0;
}

__global__ void k_count(const int* __restrict__ dst, int* __restrict__ cnt, int E) {
    int i = blockIdx.x * blockDim.x + threadIdx.x;
    if (i < E) atomicAdd(&cnt[dst[i]], 1);
}

// dinv[n] = rsqrt(cnt[n] + 1)   (self-loop included)
__global__ void k_dinv(const int* __restrict__ cnt, float* __restrict__ dinv, int N) {
    int i = blockIdx.x * blockDim.x + threadIdx.x;
    if (i < N) dinv[i] = rsqrtf((float)cnt[i] + 1.0f);
}

// ======================= exclusive scan (3 kernels, tile=1024) =======================
#define STILE 1024

__global__ void k_scan_partial(const int* __restrict__ cnt, int* __restrict__ part, int N) {
    __shared__ int s[256];
    int base = blockIdx.x * STILE;
    int t = threadIdx.x;
    int sum = 0;
#pragma unroll
    for (int k = 0; k < 4; ++k) {
        int i = base + t * 4 + k;
        if (i < N) sum += cnt[i];
    }
    s[t] = sum; __syncthreads();
    for (int off = 128; off > 0; off >>= 1) {
        if (t < off) s[t] += s[t + off];
        __syncthreads();
    }
    if (t == 0) part[blockIdx.x] = s[0];
}

// single block, running-carry exclusive scan of part[0..nTiles)
__global__ void k_scan_top(int* __restrict__ part, int nTiles) {
    __shared__ int s[256];
    int t = threadIdx.x;
    int carry = 0;
    for (int base = 0; base < nTiles; base += 256) {
        int i = base + t;
        int v = (i < nTiles) ? part[i] : 0;
        s[t] = v; __syncthreads();
        for (int o = 1; o < 256; o <<= 1) {
            int add = (t >= o) ? s[t - o] : 0;
            __syncthreads();
            s[t] += add;
            __syncthreads();
        }
        if (i < nTiles) part[i] = (s[t] - v) + carry;   // exclusive + carry
        __syncthreads();
        carry += s[255];
        __syncthreads();
    }
}

__global__ void k_scan_final(const int* __restrict__ cnt, const int* __restrict__ part,
                             int* __restrict__ offs, int* __restrict__ cur, int N) {
    __shared__ int s[256];
    int base = blockIdx.x * STILE;
    int t = threadIdx.x;
    int v[4]; int sum = 0;
#pragma unroll
    for (int k = 0; k < 4; ++k) {
        int i = base + t * 4 + k;
        v[k] = (i < N) ? cnt[i] : 0;
        sum += v[k];
    }
    s[t] = sum; __syncthreads();
    for (int o = 1; o < 256; o <<= 1) {
        int add = (t >= o) ? s[t - o] : 0;
        __syncthreads();
        s[t] += add;
        __syncthreads();
    }
    int excl = (s[t] - sum) + part[blockIdx.x];
#pragma unroll
    for (int k = 0; k < 4; ++k) {
        int i = base + t * 4 + k;
        if (i < N) { offs[i] = excl; cur[i] = excl; }
        excl += v[k];
    }
}

// ======================= CSR fill =======================
__global__ void k_fill(const int* __restrict__ src, const int* __restrict__ dst,
                       int* __restrict__ cur, int* __restrict__ csr, int E) {
    int e = blockIdx.x * blockDim.x + threadIdx.x;
    if (e < E) {
        int d = dst[e];
        int p = atomicAdd(&cur[d], 1);
        csr[p] = src[e];
    }
}

// ======================= aggregation: one wave per node, no atomics =======================
__global__ __launch_bounds__(256) void k_aggregate(const float* __restrict__ x,
                                                   const float* __restrict__ dinv,
                                                   const int* __restrict__ offs,
                                                   const int* __restrict__ cnt,
                                                   const int* __restrict__ csr,
                                                   float* __restrict__ out, int N) {
    int wid = (blockIdx.x * blockDim.x + threadIdx.x) >> 6;
    int lane = threadIdx.x & 63;
    if (wid >= N) return;
    int n = __builtin_amdgcn_readfirstlane(wid);   // wave-uniform node id

    float di = dinv[n];
    int start = offs[n];
    int m = cnt[n];

    // self-loop: dinv[n]^2 * x[n]
    float2 a = ((const float2*)(x + (size_t)n * FEAT))[lane];
    float sl = di * di;
    float2 acc = make_float2(a.x * sl, a.y * sl);

    int i = 0;
    for (; i + 4 <= m; i += 4) {
        int s0 = csr[start + i];
        int s1 = csr[start + i + 1];
        int s2 = csr[start + i + 2];
        int s3 = csr[start + i + 3];
        float n0 = dinv[s0] * di, n1 = dinv[s1] * di, n2 = dinv[s2] * di, n3 = dinv[s3] * di;
        float2 v0 = ((const float2*)(x + (size_t)s0 * FEAT))[lane];
        float2 v1 = ((const float2*)(x + (size_t)s1 * FEAT))[lane];
        float2 v2 = ((const float2*)(x + (size_t)s2 * FEAT))[lane];
        float2 v3 = ((const float2*)(x + (size_t)s3 * FEAT))[lane];
        acc.x += n0 * v0.x; acc.y += n0 * v0.y;
        acc.x += n1 * v1.x; acc.y += n1 * v1.y;
        acc.x += n2 * v2.x; acc.y += n2 * v2.y;
        acc.x += n3 * v3.x; acc.y += n3 * v3.y;
    }
    for (; i < m; ++i) {
        int s0 = csr[start + i];
        float n0 = dinv[s0] * di;
        float2 v0 = ((const float2*)(x + (size_t)s0 * FEAT))[lane];
        acc.x += n0 * v0.x; acc.y += n0 * v0.y;
    }
    ((float2*)(out + (size_t)n * FEAT))[lane] = acc;
}

// ======================= in-place GEMM: out = out @ W + b =======================
__global__ __launch_bounds__(256) void k_gemm_inplace(float* __restrict__ out,
                                                      const float* __restrict__ W,
                                                      const float* __restrict__ b, int N) {
    __shared__ float Wl[FEAT * FEAT];  // 64 KB
    int tid = threadIdx.x;
    for (int i = tid; i < FEAT * FEAT / 4; i += 256)
        ((float4*)Wl)[i] = ((const float4*)W)[i];
    __syncthreads();

    int j = tid & 127;
    int half = tid >> 7;
    int row0 = blockIdx.x * 16 + half * 8;
    row0 = __builtin_amdgcn_readfirstlane(row0);

    float bj = b[j];
    float acc[8];
#pragma unroll
    for (int r = 0; r < 8; ++r) acc[r] = bj;

    const float* Y = out + (size_t)row0 * FEAT;
    bool full = (row0 + 8 <= N);
    if (full) {
#pragma unroll 4
        for (int f = 0; f < FEAT; ++f) {
            float w = Wl[f * FEAT + j];
#pragma unroll
            for (int r = 0; r < 8; ++r) acc[r] += w * Y[(size_t)r * FEAT + f];
        }
    } else {
        for (int f = 0; f < FEAT; ++f) {
            float w = Wl[f * FEAT + j];
            for (int r = 0; r < 8; ++r)
                if (row0 + r < N) acc[r] += w * Y[(size_t)r * FEAT + f];
        }
    }
    __syncthreads();
    if (full) {
#pragma unroll
        for (int r = 0; r < 8; ++r) out[(size_t)(row0 + r) * FEAT + j] = acc[r];
    } else {
        for (int r = 0; r < 8; ++r)
            if (row0 + r < N) out[(size_t)(row0 + r) * FEAT + j] = acc[r];
    }
}

// ======================= fallback (R1 atomic path) =======================
__global__ void k_deg_initf(float* __restrict__ deg, int N) {
    int i = blockIdx.x * blockDim.x + threadIdx.x;
    if (i < N) deg[i] = 1.0f;
}
__global__ void k_deg_countf(const int* __restrict__ dst, float* __restrict__ deg, int E) {
    int i = blockIdx.x * blockDim.x + threadIdx.x;
    if (i < E) atomicAdd(&deg[dst[i]], 1.0f);
}
__global__ void k_rsqrtf_(float* __restrict__ deg, int N) {
    int i = blockIdx.x * blockDim.x + threadIdx.x;
    if (i < N) deg[i] = rsqrtf(deg[i]);
}
__global__ void k_selfloop(const float* __restrict__ x, const float* __restrict__ dinv,
                           float* __restrict__ out, int N) {
    int t = blockIdx.x * blockDim.x + threadIdx.x;
    int n = t >> 5, c = t & 31;
    if (n >= N) return;
    float s = dinv[n]; s *= s;
    float4 v = ((const float4*)(x + (size_t)n * FEAT))[c];
    v.x *= s; v.y *= s; v.z *= s; v.w *= s;
    ((float4*)(out + (size_t)n * FEAT))[c] = v;
}
__global__ void k_scatter(const int* __restrict__ src, const int* __restrict__ dst,
                          const float* __restrict__ dinv, const float* __restrict__ x,
                          float* __restrict__ out, int E) {
    long long gid = (long long)blockIdx.x * blockDim.x + threadIdx.x;
    long long e = gid >> 6;
    int lane = threadIdx.x & 63;
    if (e >= E) return;
    int s = src[e], d = dst[e];
    float nrm = dinv[s] * dinv[d];
    const float* xs = x + (size_t)s * FEAT;
    float* od = out + (size_t)d * FEAT;
    atomicAdd(&od[lane],      nrm * xs[lane]);
    atomicAdd(&od[lane + 64], nrm * xs[lane + 64]);
}

// ======================= launch =======================
extern "C" void kernel_launch(void* const* d_in, const int* in_sizes, int n_in,
                              void* d_out, int out_size, void* d_ws, size_t ws_size,
                              hipStream_t stream) {
    const float* x = (const float*)d_in[0];
    const int*   ei = (const int*)d_in[1];
    const float* W = (const float*)d_in[2];
    const float* b = (const float*)d_in[3];
    float* out = (float*)d_out;

    int N = in_sizes[0] / FEAT;
    int E = in_sizes[1] / 2;
    const int* src = ei;
    const int* dst = ei + E;

    const int bs = 256;
    int nTiles = (N + STILE - 1) / STILE;

    size_t need = ((size_t)4 * N + (size_t)E + (size_t)nTiles) * 4;
    if (ws_size >= need) {
        // ws layout: dinv[N] f32 | cnt[N] i32 | offs[N] i32 | cur[N] i32 | part[nTiles] i32 | csr[E] i32
        float* dinv = (float*)d_ws;
        int* cnt  = (int*)d_ws + N;
        int* offs = (int*)d_ws + 2 * (size_t)N;
        int* cur  = (int*)d_ws + 3 * (size_t)N;
        int* part = (int*)d_ws + 4 * (size_t)N;
        int* csr  = (int*)d_ws + 4 * (size_t)N + nTiles;

        k_zero_i32<<<(N + bs - 1) / bs, bs, 0, stream>>>(cnt, N);
        k_count<<<(E + bs - 1) / bs, bs, 0, stream>>>(dst, cnt, E);
        k_dinv<<<(N + bs - 1) / bs, bs, 0, stream>>>(cnt, dinv, N);
        k_scan_partial<<<nTiles, 256, 0, stream>>>(cnt, part, N);
        k_scan_top<<<1, 256, 0, stream>>>(part, nTiles);
        k_scan_final<<<nTiles, 256, 0, stream>>>(cnt, part, offs, cur, N);
        k_fill<<<(E + bs - 1) / bs, bs, 0, stream>>>(src, dst, cur, csr, E);

        long long t_ag = (long long)N * 64;
        k_aggregate<<<(int)((t_ag + bs - 1) / bs), bs, 0, stream>>>(x, dinv, offs, cnt, csr, out, N);
    } else {
        float* deg = (float*)d_ws;
        k_deg_initf<<<(N + bs - 1) / bs, bs, 0, stream>>>(deg, N);
        k_deg_countf<<<(E + bs - 1) / bs, bs, 0, stream>>>(dst, deg, E);
        k_rsqrtf_<<<(N + bs - 1) / bs, bs, 0, stream>>>(deg, N);
        long long t_sl = (long long)N * 32;
        k_selfloop<<<(int)((t_sl + bs - 1) / bs), bs, 0, stream>>>(x, deg, out, N);
        long long t_sc = (long long)E * 64;
        k_scatter<<<(int)((t_sc + bs - 1) / bs), bs, 0, stream>>>(src, dst, deg, x, out, E);
    }

    k_gemm_inplace<<<(N + 15) / 16, 256, 0, stream>>>(out, W, b, N);
}